// Round 19
// baseline (339.584 us; speedup 1.0000x reference)
//
#include <hip/hip_runtime.h>
#include <stdint.h>

#define B_ 4
#define N_ 4096
#define C1_ 58
#define K_ 32
#define EPS_ 1e-5f

typedef __attribute__((ext_vector_type(8))) short bf16x8;
typedef __attribute__((ext_vector_type(4))) float f32x4;

static __device__ __forceinline__ float bf2f(unsigned short u){
  return __uint_as_float(((unsigned int)u) << 16);
}
static __device__ __forceinline__ unsigned short f2bf(float f){
  unsigned int x = __float_as_uint(f);
  x = (x + 0x7FFFu + ((x >> 16) & 1u)) >> 16;
  return (unsigned short)x;
}
// packed RNE f32->bf16 pair: low word = lo, high word = hi
static __device__ __forceinline__ unsigned int cvt_pk_bf16(float lo, float hi){
  unsigned int r;
  asm("v_cvt_pk_bf16_f32 %0, %1, %2" : "=v"(r) : "v"(lo), "v"(hi));
  return r;
}
// XCD-pair <-> batch swizzle: XCDs {2b,2b+1} own batch b (blockIdx round-robins XCDs)
#define XCD_SWZ(bid, b, sub)                 \
  const int b   = ((bid) & 7) >> 1;          \
  const int sub = (((bid) >> 3) << 1) | ((bid) & 1);

// ---------------- ball query (wave-parallel) ----------------
__global__ __launch_bounds__(256) void ball_kernel(const float* __restrict__ xyz,
                                                   int* __restrict__ inds){
  XCD_SWZ(blockIdx.x, b, sub)
  const int w = threadIdx.x >> 6;
  const int wid = b * N_ + sub * 4 + w;
  const int lane = threadIdx.x & 63;
  const int n = wid & (N_ - 1);
  const float* xb = xyz + (size_t)b * N_ * 3;
  const float qx = xb[n*3+0], qy = xb[n*3+1], qz = xb[n*3+2];
  const float R2 = (float)(0.3 * 0.3);
  int* outp = inds + (size_t)wid * K_;
  int cnt = 0;
  int first = -1;
  for (int j0 = 0; j0 < N_ && cnt < K_; j0 += 64){
    const int j = j0 + lane;
    float dx = xb[j*3+0] - qx;
    float dy = xb[j*3+1] - qy;
    float dz = xb[j*3+2] - qz;
    float s = __fadd_rn(__fadd_rn(__fmul_rn(dx,dx), __fmul_rn(dy,dy)), __fmul_rn(dz,dz));
    bool p = (s <= R2);
    unsigned long long mask = __ballot(p);
    if (p){
      int pos = cnt + __popcll(mask & ((1ull << lane) - 1ull));
      if (pos < K_) outp[pos] = j;
    }
    if (first < 0 && mask) first = j0 + __builtin_ctzll(mask);
    cnt += __popcll(mask);
  }
  if (lane < K_ && lane >= cnt) outp[lane] = first;
}

// ---------------- P/Q decomposition of conv0 ----------------
__global__ __launch_bounds__(256)
void pq_kernel(const float* __restrict__ feature, const float* __restrict__ xyz,
               const float* __restrict__ W0g, const float* __restrict__ W2g,
               float* __restrict__ P, unsigned short* __restrict__ Q,
               unsigned short* __restrict__ W2bf)
{
  __shared__ float W0l[64 * 65];
  __shared__ float vql[32][64];
  const int t = threadIdx.x, bid = blockIdx.x;      // grid 512
  XCD_SWZ(bid, b, sub)                              // sub in [0,128)

  if (bid == 0){
    for (int i = t; i < 128 * 64; i += 256) W2bf[i] = f2bf(W2g[i]);
  }
  #pragma unroll
  for (int i = 0; i < 16; ++i){
    int idx = i * 256 + t;
    W0l[(idx >> 6) * 65 + (idx & 63)] = W0g[idx];
  }
  const int gpt0 = b * N_ + sub * 32;
  const size_t pb = (size_t)b * N_;
  #pragma unroll
  for (int i = 0; i < 8; ++i){
    int task = i * 256 + t;
    int r = task >> 6, c = task & 63;
    int n = (gpt0 + r) & (N_ - 1);
    float val = 0.f;
    if (c < 3)       val = xyz[(pb + n) * 3 + c];
    else if (c < 61) val = feature[(pb + n) * C1_ + (c - 3)];
    vql[r][c] = val;
  }
  __syncthreads();

  const int o = t & 63;
  const int r0 = t >> 6;
  #pragma unroll
  for (int it = 0; it < 8; ++it){
    int r = r0 + it * 4;
    float q0 = 0.f, q1 = 0.f;
    #pragma unroll
    for (int i = 0; i < 60; i += 2){
      q0 = fmaf(W0l[o*65 + 3 + i],     vql[r][i],     q0);
      q1 = fmaf(W0l[o*65 + 3 + i + 1], vql[r][i + 1], q1);
    }
    q0 = fmaf(W0l[o*65 + 3 + 60], vql[r][60], q0);
    float qv = q0 + q1;
    float p = 0.f;
    #pragma unroll
    for (int c = 0; c < 3; ++c)
      p = fmaf(W0l[o*65 + c] - W0l[o*65 + c + 3], vql[r][c], p);
    size_t gpt = (size_t)gpt0 + r;
    P[gpt * 64 + o] = p;
    Q[gpt * 64 + o] = f2bf(qv);
  }
}

// ---------------- stats0: stream y0 = P[n]+Q[idx] ----------------
__global__ __launch_bounds__(256)
void stats0_kernel(const int* __restrict__ inds, const float* __restrict__ P,
                   const unsigned short* __restrict__ Q, float* __restrict__ partials)
{
  const int t = threadIdx.x, bid = blockIdx.x;
  XCD_SWZ(bid, b, sub)                              // sub in [0,128)
  const size_t row0 = ((size_t)b << 17) + (size_t)sub * 1024;
  const int c8 = t & 7;
  float s = 0.f, q = 0.f;
  for (int i = 0; i < 32; ++i){
    size_t task = (size_t)i * 256 + t;
    size_t row = row0 + (task >> 3);
    int idx = inds[row];
    size_t pt = row >> 5;
    size_t qpt = ((size_t)b << 12) + idx;
    const float4* pp = (const float4*)(P + pt * 64 + c8 * 8);
    float4 pa = pp[0], pb = pp[1];
    bf16x8 qv = *(const bf16x8*)(Q + qpt * 64 + c8 * 8);
    float pv[8] = {pa.x, pa.y, pa.z, pa.w, pb.x, pb.y, pb.z, pb.w};
    #pragma unroll
    for (int j = 0; j < 8; ++j){
      float y = pv[j] + bf2f((unsigned short)qv[j]);
      s += y; q = fmaf(y, y, q);
    }
  }
  s += __shfl_xor(s, 1, 64);  q += __shfl_xor(q, 1, 64);
  s += __shfl_xor(s, 2, 64);  q += __shfl_xor(q, 2, 64);
  s += __shfl_xor(s, 8, 64);  q += __shfl_xor(q, 8, 64);
  s += __shfl_xor(s, 16, 64); q += __shfl_xor(q, 16, 64);
  s += __shfl_xor(s, 32, 64); q += __shfl_xor(q, 32, 64);
  const int lane = t & 63, w = t >> 6;
  float* out = partials + ((size_t)(b * 512 + sub * 4 + w)) * 4;
  if (lane == 0){ out[0] = s; out[1] = q; }
  if (lane == 4){ out[2] = s; out[3] = q; }
}

// ---------------- fused conv chain, dbuf pipeline, spill-free regalloc ----------------
// Block 512 thr (8 waves); 4 tiles x 256 rows; grid 512; XCD-batch swizzle.
// __launch_bounds__(512, 4): LDS caps us at 2 blocks/CU (= 4 waves/EU), so let
// regalloc use up to 512 VGPR instead of spilling at 128.
template<int DEPTH>
__global__ __launch_bounds__(512, 4)
void conv_chain(const int* __restrict__ inds, const float* __restrict__ P,
                const unsigned short* __restrict__ Q,
                const float* __restrict__ sc0, const float* __restrict__ sb0,
                const float* __restrict__ W1g, const unsigned short* __restrict__ W2bf,
                const float* __restrict__ sc1, const float* __restrict__ sb1,
                float* __restrict__ partials, float* __restrict__ ymax,
                float* __restrict__ ymin)
{
  constexpr int TILES = 4;
  constexpr int NGF = (DEPTH == 2) ? 4 : 2;
  constexpr int NG2 = NGF * 2;
  __shared__ unsigned short W1l[64 * 64];        // 8 KB
  __shared__ unsigned short Xl[2][256 * 64];     // 64 KB dbuf
  __shared__ float spart[8][NG2];

  const int t = threadIdx.x, bid = blockIdx.x;   // grid 512
  XCD_SWZ(bid, b, sub)                           // sub in [0,128)
  const size_t blk_row0 = ((size_t)b << 17) + (size_t)sub * 1024;
  const int lane = t & 63, w = t >> 6;
  const int col = lane & 15, quad = lane >> 4;
  const int c8 = t & 7;

  float s0r[8], b0r[8];
  #pragma unroll
  for (int j = 0; j < 8; ++j){
    s0r[j] = sc0[b * 64 + c8 * 8 + j];
    b0r[j] = sb0[b * 64 + c8 * 8 + j];
  }
  float s1r[4], b1r[4];
  if constexpr (DEPTH == 2){
    #pragma unroll
    for (int nt = 0; nt < 4; ++nt){
      s1r[nt] = sc1[b * 64 + nt * 16 + col];
      b1r[nt] = sb1[b * 64 + nt * 16 + col];
    }
  }

  // stage W1 (512 tasks, one each)
  {
    int ch = t >> 3, c = t & 7;
    const float* wr = W1g + ch * 64 + c * 8;
    bf16x8 v;
    #pragma unroll
    for (int j = 0; j < 8; ++j) v[j] = (short)f2bf(wr[j]);
    *(bf16x8*)&W1l[ch * 64 + ((c ^ (ch & 7)) * 8)] = v;
  }

  int    idxNext[4];      // indices for the NEXT tile to be Q-issued
  bf16x8 qvr[4];          // in-flight Q rows

  auto load_idx = [&](int tile){
    const size_t row0 = blk_row0 + (size_t)tile * 256;
    #pragma unroll
    for (int i = 0; i < 4; ++i)
      idxNext[i] = inds[row0 + ((i * 512 + t) >> 3)];
  };
  auto issueQ = [&](){
    #pragma unroll
    for (int i = 0; i < 4; ++i){
      size_t qpt = ((size_t)b << 12) + idxNext[i];
      qvr[i] = *(const bf16x8*)(Q + qpt * 64 + c8 * 8);
    }
  };
  auto writeT = [&](int tile, int buf){
    const size_t row0 = blk_row0 + (size_t)tile * 256;
    #pragma unroll
    for (int i = 0; i < 4; ++i){
      int r = (i * 512 + t) >> 3;
      size_t pt = (row0 + r) >> 5;
      const float4* pp = (const float4*)(P + pt * 64 + c8 * 8);
      float4 pa = pp[0], pb = pp[1];
      float pv[8] = {pa.x, pa.y, pa.z, pa.w, pb.x, pb.y, pb.z, pb.w};
      float a[8];
      #pragma unroll
      for (int j = 0; j < 8; ++j){
        float y = pv[j] + bf2f((unsigned short)qvr[i][j]);
        float v = fmaf(y, s0r[j], b0r[j]);
        a[j] = fmaxf(v, 0.f);
      }
      unsigned int pk[4];
      #pragma unroll
      for (int j = 0; j < 4; ++j) pk[j] = cvt_pk_bf16(a[2*j], a[2*j+1]);
      unsigned int* dst = (unsigned int*)&Xl[buf][r * 64 + ((c8 ^ (r & 7)) * 8)];
      #pragma unroll
      for (int j = 0; j < 4; ++j) dst[j] = pk[j];
    }
  };

  float sg[NGF], qg[NGF];
  #pragma unroll
  for (int g = 0; g < NGF; ++g){ sg[g] = 0.f; qg[g] = 0.f; }

  // prologue: idx(0) -> Q(0) -> idx(1) in flight -> stage tile 0
  load_idx(0);
  issueQ();
  load_idx(1);
  writeT(0, 0);

  for (int tile = 0; tile < TILES; ++tile){
    const int cur = tile & 1;
    const size_t row0 = blk_row0 + (size_t)tile * 256;
    __syncthreads();
    // issue next tile's Q gathers: idxNext was loaded a full tile ago -> resolved
    if (tile + 1 < TILES){
      issueQ();
      if (tile + 2 < TILES) load_idx(tile + 2);   // in flight under compute
    }

    float cmx[(DEPTH == 2) ? 8 : 1], cmn[(DEPTH == 2) ? 8 : 1];
    if constexpr (DEPTH == 2){
      #pragma unroll
      for (int nt = 0; nt < 8; ++nt){ cmx[nt] = -1e30f; cmn[nt] = 1e30f; }
    }

    #pragma unroll
    for (int mi = 0; mi < 2; ++mi){
      const int r = w * 32 + mi * 16 + col;
      bf16x8 afr[2];
      #pragma unroll
      for (int kt = 0; kt < 2; ++kt)
        afr[kt] = *(const bf16x8*)&Xl[cur][r * 64 + (((kt * 4 + quad) ^ (r & 7)) * 8)];
      f32x4 acc1[4];
      #pragma unroll
      for (int nt = 0; nt < 4; ++nt) acc1[nt] = (f32x4){0.f,0.f,0.f,0.f};
      #pragma unroll
      for (int kt = 0; kt < 2; ++kt)
        #pragma unroll
        for (int nt = 0; nt < 4; ++nt){
          int ch = nt * 16 + col;
          bf16x8 bfr = *(const bf16x8*)&W1l[ch * 64 + (((kt * 4 + quad) ^ (ch & 7)) * 8)];
          acc1[nt] = __builtin_amdgcn_mfma_f32_16x16x32_bf16(afr[kt], bfr, acc1[nt], 0, 0, 0);
        }

      if constexpr (DEPTH == 1){
        #pragma unroll
        for (int nt = 0; nt < 4; ++nt)
          #pragma unroll
          for (int rg = 0; rg < 4; ++rg){
            float y = acc1[nt][rg];
            sg[nt >> 1] += y;
            qg[nt >> 1] = fmaf(y, y, qg[nt >> 1]);
          }
      } else {
        #pragma unroll
        for (int nt = 0; nt < 4; ++nt)
          #pragma unroll
          for (int rg = 0; rg < 4; ++rg){
            int rr = w * 32 + mi * 16 + quad * 4 + rg;
            int ch = nt * 16 + col;
            float v = fmaf(acc1[nt][rg], s1r[nt], b1r[nt]);
            v = fmaxf(v, 0.f);
            Xl[cur][rr * 64 + (((ch >> 3) ^ (rr & 7)) * 8) + (ch & 7)] = f2bf(v);
          }
        // conv2 (COUT=128), W2 JIT from global bf16; reuse afr for fragments
        #pragma unroll
        for (int kt = 0; kt < 2; ++kt)
          afr[kt] = *(const bf16x8*)&Xl[cur][r * 64 + (((kt * 4 + quad) ^ (r & 7)) * 8)];
        f32x4 acc2[8];
        #pragma unroll
        for (int nt = 0; nt < 8; ++nt) acc2[nt] = (f32x4){0.f,0.f,0.f,0.f};
        #pragma unroll
        for (int kt = 0; kt < 2; ++kt)
          #pragma unroll
          for (int nt = 0; nt < 8; ++nt){
            int ch = nt * 16 + col;
            bf16x8 bfr = *(const bf16x8*)&W2bf[ch * 64 + (kt * 4 + quad) * 8];
            acc2[nt] = __builtin_amdgcn_mfma_f32_16x16x32_bf16(afr[kt], bfr, acc2[nt], 0, 0, 0);
          }
        #pragma unroll
        for (int nt = 0; nt < 8; ++nt)
          #pragma unroll
          for (int rg = 0; rg < 4; ++rg){
            float y = acc2[nt][rg];
            sg[nt >> 1] += y;
            qg[nt >> 1] = fmaf(y, y, qg[nt >> 1]);
            cmx[nt] = fmaxf(cmx[nt], y);
            cmn[nt] = fminf(cmn[nt], y);
          }
      }
    }

    if constexpr (DEPTH == 2){
      #pragma unroll
      for (int nt = 0; nt < 8; ++nt){
        cmx[nt] = fmaxf(cmx[nt], __shfl_xor(cmx[nt], 16, 64));
        cmx[nt] = fmaxf(cmx[nt], __shfl_xor(cmx[nt], 32, 64));
        cmn[nt] = fminf(cmn[nt], __shfl_xor(cmn[nt], 16, 64));
        cmn[nt] = fminf(cmn[nt], __shfl_xor(cmn[nt], 32, 64));
      }
      if (quad == 0){
        size_t pt = (row0 >> 5) + w;
        #pragma unroll
        for (int nt = 0; nt < 8; ++nt){
          ymax[pt * 128 + nt * 16 + col] = cmx[nt];
          ymin[pt * 128 + nt * 16 + col] = cmn[nt];
        }
      }
    }

    if (tile + 1 < TILES) writeT(tile + 1, cur ^ 1);   // Q wait lands here, post-compute
  }

  // epilogue: wave shfl-reduce -> LDS -> one record per block (batch-major)
  #pragma unroll
  for (int g = 0; g < NGF; ++g){
    #pragma unroll
    for (int off = 32; off > 0; off >>= 1){
      sg[g] += __shfl_down(sg[g], off, 64);
      qg[g] += __shfl_down(qg[g], off, 64);
    }
  }
  if (lane == 0){
    #pragma unroll
    for (int g = 0; g < NGF; ++g){
      spart[w][g * 2 + 0] = sg[g];
      spart[w][g * 2 + 1] = qg[g];
    }
  }
  __syncthreads();
  if (t < NG2){
    float v = 0.f;
    #pragma unroll
    for (int ww = 0; ww < 8; ++ww) v += spart[ww][t];
    partials[(size_t)(b * 128 + sub) * NG2 + t] = v;   // [b][128][NG2]
  }
}

// ---------------- finalize: unrolled parallel reduce, fold GN affine ----------------
template<int NCH, int NPER>
__global__ __launch_bounds__(256)
void finalize_kernel(const float* __restrict__ partials,
                     const float* __restrict__ g, const float* __restrict__ bb,
                     float* __restrict__ sc, float* __restrict__ sb){
  constexpr int NG2 = (NCH / 32) * 2;
  constexpr int NSLOTS = 4 * NG2;
  constexpr int TPS = 256 / NSLOTS;
  __shared__ float st[NSLOTS];
  const int t = threadIdx.x;
  const int slot = t / TPS, j = t % TPS;
  const int b = slot / NG2, idx = slot % NG2;
  float acc = 0.f;
  #pragma unroll
  for (int i = 0; i < NPER / TPS; ++i)
    acc += partials[((size_t)b * NPER + j + i * TPS) * NG2 + idx];
  #pragma unroll
  for (int off = TPS >> 1; off > 0; off >>= 1)
    acc += __shfl_down(acc, off, 64);
  if (j == 0) st[slot] = acc;
  __syncthreads();
  for (int c0 = t; c0 < 4 * NCH; c0 += 256){
    int b2 = c0 / NCH, c = c0 % NCH, grp = c >> 5;
    float s = st[b2 * NG2 + grp * 2 + 0], q = st[b2 * NG2 + grp * 2 + 1];
    const float cnt = 4194304.f;
    float mean = s / cnt;
    float var = q / cnt - mean * mean;
    float rstd = 1.f / sqrtf(var + EPS_);
    float scale = rstd * g[c];
    sc[b2 * NCH + c] = scale;
    sb[b2 * NCH + c] = bb[c] - mean * scale;
  }
}

// ---------------- final: GN2+relu on k-extremum, transpose ----------------
__global__ __launch_bounds__(256)
void out_kernel(const float* __restrict__ ymax, const float* __restrict__ ymin,
                const float* __restrict__ sc2, const float* __restrict__ sb2,
                float* __restrict__ out){
  __shared__ float tile[64 * 129];
  const int t = threadIdx.x;
  const int b = blockIdx.y;
  const int n0 = blockIdx.x * 64;
  const float4* mx4 = (const float4*)(ymax + ((size_t)b * N_ + n0) * 128);
  const float4* mn4 = (const float4*)(ymin + ((size_t)b * N_ + n0) * 128);
  #pragma unroll
  for (int i = 0; i < 8; ++i){
    int e4 = i * 256 + t;
    int nl = e4 >> 5;
    int ch0 = (e4 & 31) * 4;
    float4 vx = mx4[e4], vn = mn4[e4];
    #pragma unroll
    for (int j = 0; j < 4; ++j){
      float slope = sc2[b*128 + ch0 + j];
      float off   = sb2[b*128 + ch0 + j];
      float y = (slope >= 0.f) ? ((const float*)&vx)[j] : ((const float*)&vn)[j];
      float v = fmaf(y, slope, off);
      tile[nl*129 + ch0 + j] = v > 0.f ? v : 0.f;
    }
  }
  __syncthreads();
  const int ch = t >> 1, h = t & 1;
  float* orow = out + ((size_t)b * 128 + ch) * N_ + n0 + h * 32;
  #pragma unroll
  for (int jj = 0; jj < 8; ++jj){
    float4 v;
    #pragma unroll
    for (int c = 0; c < 4; ++c)
      ((float*)&v)[c] = tile[(h*32 + jj*4 + c)*129 + ch];
    ((float4*)orow)[jj] = v;
  }
}

extern "C" void kernel_launch(void* const* d_in, const int* in_sizes, int n_in,
                              void* d_out, int out_size, void* d_ws, size_t ws_size,
                              hipStream_t stream) {
  const float* feature = (const float*)d_in[0];
  const float* xyz     = (const float*)d_in[1];
  const float* W0 = (const float*)d_in[2];
  const float* g0 = (const float*)d_in[3];
  const float* b0 = (const float*)d_in[4];
  const float* W1 = (const float*)d_in[5];
  const float* g1 = (const float*)d_in[6];
  const float* b1 = (const float*)d_in[7];
  const float* W2 = (const float*)d_in[8];
  const float* g2 = (const float*)d_in[9];
  const float* b2 = (const float*)d_in[10];
  float* out = (float*)d_out;

  char* ws = (char*)d_ws;
  const size_t INDS_BYTES = (size_t)B_ * N_ * K_ * sizeof(int);   // 2 MiB
  const size_t YBYTES     = (size_t)B_ * N_ * 128 * sizeof(float);// 8 MiB each
  const size_t PBYTES     = (size_t)B_ * N_ * 64 * sizeof(float); // 4 MiB
  const size_t QBYTES     = (size_t)B_ * N_ * 64 * 2;             // 2 MiB
  int* inds            = (int*)ws;
  float* ymax          = (float*)(ws + INDS_BYTES);
  float* ymin          = (float*)(ws + INDS_BYTES + YBYTES);
  float* P             = (float*)(ws + INDS_BYTES + 2 * YBYTES);
  unsigned short* Q    = (unsigned short*)(ws + INDS_BYTES + 2 * YBYTES + PBYTES);
  unsigned short* W2bf = (unsigned short*)(ws + INDS_BYTES + 2 * YBYTES + PBYTES + QBYTES);
  float* p0 = (float*)(ws + INDS_BYTES + 2 * YBYTES + PBYTES + QBYTES + 16384);
  float* p1 = p0 + 2048 * 4;       // stats0: [4][512][4]
  float* p2 = p1 + 512 * 4;        // chain1: [4][128][4]
  float* sc0 = p2 + 512 * 8;       // chain2: [4][128][8]
  float* sb0 = sc0 + 256;
  float* sc1 = sb0 + 256;
  float* sb1 = sc1 + 256;
  float* sc2 = sb1 + 256;          // [4][128]
  float* sb2 = sc2 + 512;

  ball_kernel<<<B_ * N_ / 4, 256, 0, stream>>>(xyz, inds);
  pq_kernel<<<B_ * N_ / 32, 256, 0, stream>>>(feature, xyz, W0, W2, P, Q, W2bf);

  stats0_kernel<<<B_ * N_ * K_ / 1024, 256, 0, stream>>>(inds, P, Q, p0);
  finalize_kernel<64, 512><<<1, 256, 0, stream>>>(p0, g0, b0, sc0, sb0);

  const int GRID = 512;   // 4 tiles x 256 rows each

  conv_chain<1><<<GRID, 512, 0, stream>>>(
      inds, P, Q, sc0, sb0, W1, nullptr, nullptr, nullptr,
      p1, nullptr, nullptr);
  finalize_kernel<64, 128><<<1, 256, 0, stream>>>(p1, g1, b1, sc1, sb1);

  conv_chain<2><<<GRID, 512, 0, stream>>>(
      inds, P, Q, sc0, sb0, W1, W2bf, sc1, sb1,
      p2, ymax, ymin);
  finalize_kernel<128, 128><<<1, 256, 0, stream>>>(p2, g2, b2, sc2, sb2);

  dim3 ogrid(N_ / 64, B_);
  out_kernel<<<ogrid, 256, 0, stream>>>(ymax, ymin, sc2, sb2, out);
}

// Round 20
// 138.658 us; speedup vs baseline: 2.4491x; 2.4491x over previous
//
#include <hip/hip_runtime.h>
#include <stdint.h>

#define B_ 4
#define N_ 4096
#define C1_ 58
#define K_ 32
#define EPS_ 1e-5f

typedef __attribute__((ext_vector_type(8))) short bf16x8;
typedef __attribute__((ext_vector_type(4))) float f32x4;

static __device__ __forceinline__ float bf2f(unsigned short u){
  return __uint_as_float(((unsigned int)u) << 16);
}
static __device__ __forceinline__ unsigned short f2bf(float f){
  unsigned int x = __float_as_uint(f);
  x = (x + 0x7FFFu + ((x >> 16) & 1u)) >> 16;
  return (unsigned short)x;
}
// packed RNE f32->bf16 pair: low word = lo, high word = hi
static __device__ __forceinline__ unsigned int cvt_pk_bf16(float lo, float hi){
  unsigned int r;
  asm("v_cvt_pk_bf16_f32 %0, %1, %2" : "=v"(r) : "v"(lo), "v"(hi));
  return r;
}
// XCD-pair <-> batch swizzle: XCDs {2b,2b+1} own batch b (blockIdx round-robins XCDs)
#define XCD_SWZ(bid, b, sub)                 \
  const int b   = ((bid) & 7) >> 1;          \
  const int sub = (((bid) >> 3) << 1) | ((bid) & 1);

// ---------------- ball query (wave-parallel) ----------------
__global__ __launch_bounds__(256) void ball_kernel(const float* __restrict__ xyz,
                                                   int* __restrict__ inds){
  XCD_SWZ(blockIdx.x, b, sub)
  const int w = threadIdx.x >> 6;
  const int wid = b * N_ + sub * 4 + w;
  const int lane = threadIdx.x & 63;
  const int n = wid & (N_ - 1);
  const float* xb = xyz + (size_t)b * N_ * 3;
  const float qx = xb[n*3+0], qy = xb[n*3+1], qz = xb[n*3+2];
  const float R2 = (float)(0.3 * 0.3);
  int* outp = inds + (size_t)wid * K_;
  int cnt = 0;
  int first = -1;
  for (int j0 = 0; j0 < N_ && cnt < K_; j0 += 64){
    const int j = j0 + lane;
    float dx = xb[j*3+0] - qx;
    float dy = xb[j*3+1] - qy;
    float dz = xb[j*3+2] - qz;
    float s = __fadd_rn(__fadd_rn(__fmul_rn(dx,dx), __fmul_rn(dy,dy)), __fmul_rn(dz,dz));
    bool p = (s <= R2);
    unsigned long long mask = __ballot(p);
    if (p){
      int pos = cnt + __popcll(mask & ((1ull << lane) - 1ull));
      if (pos < K_) outp[pos] = j;
    }
    if (first < 0 && mask) first = j0 + __builtin_ctzll(mask);
    cnt += __popcll(mask);
  }
  if (lane < K_ && lane >= cnt) outp[lane] = first;
}

// ---------------- P/Q decomposition of conv0 ----------------
__global__ __launch_bounds__(256)
void pq_kernel(const float* __restrict__ feature, const float* __restrict__ xyz,
               const float* __restrict__ W0g, const float* __restrict__ W2g,
               float* __restrict__ P, unsigned short* __restrict__ Q,
               unsigned short* __restrict__ W2bf)
{
  __shared__ float W0l[64 * 65];
  __shared__ float vql[32][64];
  const int t = threadIdx.x, bid = blockIdx.x;      // grid 512
  XCD_SWZ(bid, b, sub)                              // sub in [0,128)

  if (bid == 0){
    for (int i = t; i < 128 * 64; i += 256) W2bf[i] = f2bf(W2g[i]);
  }
  #pragma unroll
  for (int i = 0; i < 16; ++i){
    int idx = i * 256 + t;
    W0l[(idx >> 6) * 65 + (idx & 63)] = W0g[idx];
  }
  const int gpt0 = b * N_ + sub * 32;
  const size_t pb = (size_t)b * N_;
  #pragma unroll
  for (int i = 0; i < 8; ++i){
    int task = i * 256 + t;
    int r = task >> 6, c = task & 63;
    int n = (gpt0 + r) & (N_ - 1);
    float val = 0.f;
    if (c < 3)       val = xyz[(pb + n) * 3 + c];
    else if (c < 61) val = feature[(pb + n) * C1_ + (c - 3)];
    vql[r][c] = val;
  }
  __syncthreads();

  const int o = t & 63;
  const int r0 = t >> 6;
  #pragma unroll
  for (int it = 0; it < 8; ++it){
    int r = r0 + it * 4;
    float q0 = 0.f, q1 = 0.f;
    #pragma unroll
    for (int i = 0; i < 60; i += 2){
      q0 = fmaf(W0l[o*65 + 3 + i],     vql[r][i],     q0);
      q1 = fmaf(W0l[o*65 + 3 + i + 1], vql[r][i + 1], q1);
    }
    q0 = fmaf(W0l[o*65 + 3 + 60], vql[r][60], q0);
    float qv = q0 + q1;
    float p = 0.f;
    #pragma unroll
    for (int c = 0; c < 3; ++c)
      p = fmaf(W0l[o*65 + c] - W0l[o*65 + c + 3], vql[r][c], p);
    size_t gpt = (size_t)gpt0 + r;
    P[gpt * 64 + o] = p;
    Q[gpt * 64 + o] = f2bf(qv);
  }
}

// ---------------- stats0: stream y0 = P[n]+Q[idx] ----------------
// Grid 2048; 256 rows/block (4x more schedulable blocks for latency hiding).
__global__ __launch_bounds__(256)
void stats0_kernel(const int* __restrict__ inds, const float* __restrict__ P,
                   const unsigned short* __restrict__ Q, float* __restrict__ partials)
{
  const int t = threadIdx.x, bid = blockIdx.x;
  XCD_SWZ(bid, b, sub)                              // sub in [0,512)
  const size_t row0 = ((size_t)b << 17) + (size_t)sub * 256;
  const int c8 = t & 7;
  float s = 0.f, q = 0.f;
  for (int i = 0; i < 8; ++i){
    size_t task = (size_t)i * 256 + t;
    size_t row = row0 + (task >> 3);
    int idx = inds[row];
    size_t pt = row >> 5;
    size_t qpt = ((size_t)b << 12) + idx;
    const float4* pp = (const float4*)(P + pt * 64 + c8 * 8);
    float4 pa = pp[0], pb = pp[1];
    bf16x8 qv = *(const bf16x8*)(Q + qpt * 64 + c8 * 8);
    float pv[8] = {pa.x, pa.y, pa.z, pa.w, pb.x, pb.y, pb.z, pb.w};
    #pragma unroll
    for (int j = 0; j < 8; ++j){
      float y = pv[j] + bf2f((unsigned short)qv[j]);
      s += y; q = fmaf(y, y, q);
    }
  }
  s += __shfl_xor(s, 1, 64);  q += __shfl_xor(q, 1, 64);
  s += __shfl_xor(s, 2, 64);  q += __shfl_xor(q, 2, 64);
  s += __shfl_xor(s, 8, 64);  q += __shfl_xor(q, 8, 64);
  s += __shfl_xor(s, 16, 64); q += __shfl_xor(q, 16, 64);
  s += __shfl_xor(s, 32, 64); q += __shfl_xor(q, 32, 64);
  const int lane = t & 63, w = t >> 6;
  float* out = partials + ((size_t)(b * 2048 + sub * 4 + w)) * 4;
  if (lane == 0){ out[0] = s; out[1] = q; }
  if (lane == 4){ out[2] = s; out[3] = q; }
}

// ---------------- fused conv chain, double-buffered tile pipeline (R16) ----------------
// Block 512 thr (8 waves); 4 tiles x 256 rows; grid 512; batch-local via XCD swizzle.
// Per tile: barrier -> issue(next: inds+Q gathers) -> compute(cur) -> write(next).
template<int DEPTH>
__global__ __launch_bounds__(512)
void conv_chain(const int* __restrict__ inds, const float* __restrict__ P,
                const unsigned short* __restrict__ Q,
                const float* __restrict__ sc0, const float* __restrict__ sb0,
                const float* __restrict__ W1g, const unsigned short* __restrict__ W2bf,
                const float* __restrict__ sc1, const float* __restrict__ sb1,
                float* __restrict__ partials, float* __restrict__ ymax,
                float* __restrict__ ymin)
{
  constexpr int TILES = 4;
  constexpr int NGF = (DEPTH == 2) ? 4 : 2;
  constexpr int NG2 = NGF * 2;
  __shared__ unsigned short W1l[64 * 64];        // 8 KB
  __shared__ unsigned short Xl[2][256 * 64];     // 64 KB dbuf
  __shared__ float spart[8][NG2];

  const int t = threadIdx.x, bid = blockIdx.x;   // grid 512
  XCD_SWZ(bid, b, sub)                           // sub in [0,128)
  const size_t blk_row0 = ((size_t)b << 17) + (size_t)sub * 1024;
  const int lane = t & 63, w = t >> 6;
  const int col = lane & 15, quad = lane >> 4;
  const int c8 = t & 7;

  float s0r[8], b0r[8];
  #pragma unroll
  for (int j = 0; j < 8; ++j){
    s0r[j] = sc0[b * 64 + c8 * 8 + j];
    b0r[j] = sb0[b * 64 + c8 * 8 + j];
  }
  float s1r[4], b1r[4];
  if constexpr (DEPTH == 2){
    #pragma unroll
    for (int nt = 0; nt < 4; ++nt){
      s1r[nt] = sc1[b * 64 + nt * 16 + col];
      b1r[nt] = sb1[b * 64 + nt * 16 + col];
    }
  }

  // stage W1 (512 tasks, one each)
  {
    int ch = t >> 3, c = t & 7;
    const float* wr = W1g + ch * 64 + c * 8;
    bf16x8 v;
    #pragma unroll
    for (int j = 0; j < 8; ++j) v[j] = (short)f2bf(wr[j]);
    *(bf16x8*)&W1l[ch * 64 + ((c ^ (ch & 7)) * 8)] = v;
  }

  // staging registers (gather prefetch: inds + Q only; P is L1/L2-hot)
  int    idxr[4];
  bf16x8 qvr[4];

  auto issue = [&](int tile){
    const size_t row0 = blk_row0 + (size_t)tile * 256;
    #pragma unroll
    for (int i = 0; i < 4; ++i)
      idxr[i] = inds[row0 + ((i * 512 + t) >> 3)];
    #pragma unroll
    for (int i = 0; i < 4; ++i){
      size_t qpt = ((size_t)b << 12) + idxr[i];
      qvr[i] = *(const bf16x8*)(Q + qpt * 64 + c8 * 8);
    }
  };

  auto writeT = [&](int tile, int buf){
    const size_t row0 = blk_row0 + (size_t)tile * 256;
    #pragma unroll
    for (int i = 0; i < 4; ++i){
      int r = (i * 512 + t) >> 3;
      size_t pt = (row0 + r) >> 5;
      const float4* pp = (const float4*)(P + pt * 64 + c8 * 8);
      float4 pa = pp[0], pb = pp[1];
      float pv[8] = {pa.x, pa.y, pa.z, pa.w, pb.x, pb.y, pb.z, pb.w};
      float a[8];
      #pragma unroll
      for (int j = 0; j < 8; ++j){
        float y = pv[j] + bf2f((unsigned short)qvr[i][j]);
        float v = fmaf(y, s0r[j], b0r[j]);
        a[j] = fmaxf(v, 0.f);
      }
      unsigned int pk[4];
      #pragma unroll
      for (int j = 0; j < 4; ++j) pk[j] = cvt_pk_bf16(a[2*j], a[2*j+1]);
      unsigned int* dst = (unsigned int*)&Xl[buf][r * 64 + ((c8 ^ (r & 7)) * 8)];
      #pragma unroll
      for (int j = 0; j < 4; ++j) dst[j] = pk[j];
    }
  };

  float sg[NGF], qg[NGF];
  #pragma unroll
  for (int g = 0; g < NGF; ++g){ sg[g] = 0.f; qg[g] = 0.f; }

  issue(0);
  writeT(0, 0);

  for (int tile = 0; tile < TILES; ++tile){
    const int cur = tile & 1;
    const size_t row0 = blk_row0 + (size_t)tile * 256;
    __syncthreads();
    if (tile + 1 < TILES) issue(tile + 1);

    float cmx[(DEPTH == 2) ? 8 : 1], cmn[(DEPTH == 2) ? 8 : 1];
    if constexpr (DEPTH == 2){
      #pragma unroll
      for (int nt = 0; nt < 8; ++nt){ cmx[nt] = -1e30f; cmn[nt] = 1e30f; }
    }

    #pragma unroll
    for (int mi = 0; mi < 2; ++mi){
      const int r = w * 32 + mi * 16 + col;
      bf16x8 afr[2];
      #pragma unroll
      for (int kt = 0; kt < 2; ++kt)
        afr[kt] = *(const bf16x8*)&Xl[cur][r * 64 + (((kt * 4 + quad) ^ (r & 7)) * 8)];
      f32x4 acc1[4];
      #pragma unroll
      for (int nt = 0; nt < 4; ++nt) acc1[nt] = (f32x4){0.f,0.f,0.f,0.f};
      #pragma unroll
      for (int kt = 0; kt < 2; ++kt)
        #pragma unroll
        for (int nt = 0; nt < 4; ++nt){
          int ch = nt * 16 + col;
          bf16x8 bfr = *(const bf16x8*)&W1l[ch * 64 + (((kt * 4 + quad) ^ (ch & 7)) * 8)];
          acc1[nt] = __builtin_amdgcn_mfma_f32_16x16x32_bf16(afr[kt], bfr, acc1[nt], 0, 0, 0);
        }

      if constexpr (DEPTH == 1){
        #pragma unroll
        for (int nt = 0; nt < 4; ++nt)
          #pragma unroll
          for (int rg = 0; rg < 4; ++rg){
            float y = acc1[nt][rg];
            sg[nt >> 1] += y;
            qg[nt >> 1] = fmaf(y, y, qg[nt >> 1]);
          }
      } else {
        #pragma unroll
        for (int nt = 0; nt < 4; ++nt)
          #pragma unroll
          for (int rg = 0; rg < 4; ++rg){
            int rr = w * 32 + mi * 16 + quad * 4 + rg;
            int ch = nt * 16 + col;
            float v = fmaf(acc1[nt][rg], s1r[nt], b1r[nt]);
            v = fmaxf(v, 0.f);
            Xl[cur][rr * 64 + (((ch >> 3) ^ (rr & 7)) * 8) + (ch & 7)] = f2bf(v);
          }
        bf16x8 a2f[2];
        #pragma unroll
        for (int kt = 0; kt < 2; ++kt)
          a2f[kt] = *(const bf16x8*)&Xl[cur][r * 64 + (((kt * 4 + quad) ^ (r & 7)) * 8)];
        f32x4 acc2[8];
        #pragma unroll
        for (int nt = 0; nt < 8; ++nt) acc2[nt] = (f32x4){0.f,0.f,0.f,0.f};
        #pragma unroll
        for (int kt = 0; kt < 2; ++kt)
          #pragma unroll
          for (int nt = 0; nt < 8; ++nt){
            int ch = nt * 16 + col;
            bf16x8 bfr = *(const bf16x8*)&W2bf[ch * 64 + (kt * 4 + quad) * 8];
            acc2[nt] = __builtin_amdgcn_mfma_f32_16x16x32_bf16(a2f[kt], bfr, acc2[nt], 0, 0, 0);
          }
        #pragma unroll
        for (int nt = 0; nt < 8; ++nt)
          #pragma unroll
          for (int rg = 0; rg < 4; ++rg){
            float y = acc2[nt][rg];
            sg[nt >> 1] += y;
            qg[nt >> 1] = fmaf(y, y, qg[nt >> 1]);
            cmx[nt] = fmaxf(cmx[nt], y);
            cmn[nt] = fminf(cmn[nt], y);
          }
      }
    }

    if constexpr (DEPTH == 2){
      #pragma unroll
      for (int nt = 0; nt < 8; ++nt){
        cmx[nt] = fmaxf(cmx[nt], __shfl_xor(cmx[nt], 16, 64));
        cmx[nt] = fmaxf(cmx[nt], __shfl_xor(cmx[nt], 32, 64));
        cmn[nt] = fminf(cmn[nt], __shfl_xor(cmn[nt], 16, 64));
        cmn[nt] = fminf(cmn[nt], __shfl_xor(cmn[nt], 32, 64));
      }
      if (quad == 0){
        size_t pt = (row0 >> 5) + w;
        #pragma unroll
        for (int nt = 0; nt < 8; ++nt){
          ymax[pt * 128 + nt * 16 + col] = cmx[nt];
          ymin[pt * 128 + nt * 16 + col] = cmn[nt];
        }
      }
    }

    if (tile + 1 < TILES) writeT(tile + 1, cur ^ 1);
  }

  // epilogue: wave shfl-reduce -> LDS -> one record per block (batch-major)
  #pragma unroll
  for (int g = 0; g < NGF; ++g){
    #pragma unroll
    for (int off = 32; off > 0; off >>= 1){
      sg[g] += __shfl_down(sg[g], off, 64);
      qg[g] += __shfl_down(qg[g], off, 64);
    }
  }
  if (lane == 0){
    #pragma unroll
    for (int g = 0; g < NGF; ++g){
      spart[w][g * 2 + 0] = sg[g];
      spart[w][g * 2 + 1] = qg[g];
    }
  }
  __syncthreads();
  if (t < NG2){
    float v = 0.f;
    #pragma unroll
    for (int ww = 0; ww < 8; ++ww) v += spart[ww][t];
    partials[(size_t)(b * 128 + sub) * NG2 + t] = v;   // [b][128][NG2]
  }
}

// ---------------- finalize: unrolled parallel reduce, fold GN affine ----------------
template<int NCH, int NPER>
__global__ __launch_bounds__(256)
void finalize_kernel(const float* __restrict__ partials,
                     const float* __restrict__ g, const float* __restrict__ bb,
                     float* __restrict__ sc, float* __restrict__ sb){
  constexpr int NG2 = (NCH / 32) * 2;
  constexpr int NSLOTS = 4 * NG2;
  constexpr int TPS = 256 / NSLOTS;
  __shared__ float st[NSLOTS];
  const int t = threadIdx.x;
  const int slot = t / TPS, j = t % TPS;
  const int b = slot / NG2, idx = slot % NG2;
  float acc = 0.f;
  #pragma unroll
  for (int i = 0; i < NPER / TPS; ++i)
    acc += partials[((size_t)b * NPER + j + i * TPS) * NG2 + idx];
  #pragma unroll
  for (int off = TPS >> 1; off > 0; off >>= 1)
    acc += __shfl_down(acc, off, 64);
  if (j == 0) st[slot] = acc;
  __syncthreads();
  for (int c0 = t; c0 < 4 * NCH; c0 += 256){
    int b2 = c0 / NCH, c = c0 % NCH, grp = c >> 5;
    float s = st[b2 * NG2 + grp * 2 + 0], q = st[b2 * NG2 + grp * 2 + 1];
    const float cnt = 4194304.f;
    float mean = s / cnt;
    float var = q / cnt - mean * mean;
    float rstd = 1.f / sqrtf(var + EPS_);
    float scale = rstd * g[c];
    sc[b2 * NCH + c] = scale;
    sb[b2 * NCH + c] = bb[c] - mean * scale;
  }
}

// ---------------- final: GN2+relu on k-extremum, transpose ----------------
__global__ __launch_bounds__(256)
void out_kernel(const float* __restrict__ ymax, const float* __restrict__ ymin,
                const float* __restrict__ sc2, const float* __restrict__ sb2,
                float* __restrict__ out){
  __shared__ float tile[64 * 129];
  const int t = threadIdx.x;
  const int b = blockIdx.y;
  const int n0 = blockIdx.x * 64;
  const float4* mx4 = (const float4*)(ymax + ((size_t)b * N_ + n0) * 128);
  const float4* mn4 = (const float4*)(ymin + ((size_t)b * N_ + n0) * 128);
  #pragma unroll
  for (int i = 0; i < 8; ++i){
    int e4 = i * 256 + t;
    int nl = e4 >> 5;
    int ch0 = (e4 & 31) * 4;
    float4 vx = mx4[e4], vn = mn4[e4];
    #pragma unroll
    for (int j = 0; j < 4; ++j){
      float slope = sc2[b*128 + ch0 + j];
      float off   = sb2[b*128 + ch0 + j];
      float y = (slope >= 0.f) ? ((const float*)&vx)[j] : ((const float*)&vn)[j];
      float v = fmaf(y, slope, off);
      tile[nl*129 + ch0 + j] = v > 0.f ? v : 0.f;
    }
  }
  __syncthreads();
  const int ch = t >> 1, h = t & 1;
  float* orow = out + ((size_t)b * 128 + ch) * N_ + n0 + h * 32;
  #pragma unroll
  for (int jj = 0; jj < 8; ++jj){
    float4 v;
    #pragma unroll
    for (int c = 0; c < 4; ++c)
      ((float*)&v)[c] = tile[(h*32 + jj*4 + c)*129 + ch];
    ((float4*)orow)[jj] = v;
  }
}

extern "C" void kernel_launch(void* const* d_in, const int* in_sizes, int n_in,
                              void* d_out, int out_size, void* d_ws, size_t ws_size,
                              hipStream_t stream) {
  const float* feature = (const float*)d_in[0];
  const float* xyz     = (const float*)d_in[1];
  const float* W0 = (const float*)d_in[2];
  const float* g0 = (const float*)d_in[3];
  const float* b0 = (const float*)d_in[4];
  const float* W1 = (const float*)d_in[5];
  const float* g1 = (const float*)d_in[6];
  const float* b1 = (const float*)d_in[7];
  const float* W2 = (const float*)d_in[8];
  const float* g2 = (const float*)d_in[9];
  const float* b2 = (const float*)d_in[10];
  float* out = (float*)d_out;

  char* ws = (char*)d_ws;
  const size_t INDS_BYTES = (size_t)B_ * N_ * K_ * sizeof(int);   // 2 MiB
  const size_t YBYTES     = (size_t)B_ * N_ * 128 * sizeof(float);// 8 MiB each
  const size_t PBYTES     = (size_t)B_ * N_ * 64 * sizeof(float); // 4 MiB
  const size_t QBYTES     = (size_t)B_ * N_ * 64 * 2;             // 2 MiB
  int* inds            = (int*)ws;
  float* ymax          = (float*)(ws + INDS_BYTES);
  float* ymin          = (float*)(ws + INDS_BYTES + YBYTES);
  float* P             = (float*)(ws + INDS_BYTES + 2 * YBYTES);
  unsigned short* Q    = (unsigned short*)(ws + INDS_BYTES + 2 * YBYTES + PBYTES);
  unsigned short* W2bf = (unsigned short*)(ws + INDS_BYTES + 2 * YBYTES + PBYTES + QBYTES);
  float* p0 = (float*)(ws + INDS_BYTES + 2 * YBYTES + PBYTES + QBYTES + 16384);
  float* p1 = p0 + 8192 * 4;       // stats0: [4][2048][4]
  float* p2 = p1 + 512 * 4;        // chain1: [4][128][4]
  float* sc0 = p2 + 512 * 8;       // chain2: [4][128][8]
  float* sb0 = sc0 + 256;
  float* sc1 = sb0 + 256;
  float* sb1 = sc1 + 256;
  float* sc2 = sb1 + 256;          // [4][128]
  float* sb2 = sc2 + 512;

  ball_kernel<<<B_ * N_ / 4, 256, 0, stream>>>(xyz, inds);
  pq_kernel<<<B_ * N_ / 32, 256, 0, stream>>>(feature, xyz, W0, W2, P, Q, W2bf);

  stats0_kernel<<<B_ * N_ * K_ / 256, 256, 0, stream>>>(inds, P, Q, p0);
  finalize_kernel<64, 2048><<<1, 256, 0, stream>>>(p0, g0, b0, sc0, sb0);

  const int GRID = 512;   // 4 tiles x 256 rows each

  conv_chain<1><<<GRID, 512, 0, stream>>>(
      inds, P, Q, sc0, sb0, W1, nullptr, nullptr, nullptr,
      p1, nullptr, nullptr);
  finalize_kernel<64, 128><<<1, 256, 0, stream>>>(p1, g1, b1, sc1, sb1);

  conv_chain<2><<<GRID, 512, 0, stream>>>(
      inds, P, Q, sc0, sb0, W1, W2bf, sc1, sb1,
      p2, ymax, ymin);
  finalize_kernel<128, 128><<<1, 256, 0, stream>>>(p2, g2, b2, sc2, sb2);

  dim3 ogrid(N_ / 64, B_);
  out_kernel<<<ogrid, 256, 0, stream>>>(ymax, ymin, sc2, sb2, out);
}